// Round 11
// baseline (374.915 us; speedup 1.0000x reference)
//
#include <hip/hip_runtime.h>

#define U 4096
#define S 8192
#define D 32
#define NUM_REGIONS 128
#define GA 0.1f

#define WU 16      // users per block (MFMA N axis)
#define WI 512     // items per block (4 waves x 128) -> 8 tiles/wave
#define NT 8       // t-steps per wave
#define THREADS 256
#define LCAP 256   // max users per region (expected ~32)

typedef short          frag8_t __attribute__((ext_vector_type(8)));  // 8 bf16 bits
typedef unsigned short u16x8_t __attribute__((ext_vector_type(8)));
typedef float          fx4_t   __attribute__((ext_vector_type(4)));

// split fp32x8 into hi/lo bf16 fragments: v = hi + lo to ~16 mantissa bits.
__device__ inline void split8(const float4 a, const float4 b, frag8_t& hi, frag8_t& lo) {
    u16x8_t h, l;
    float vv[8] = {a.x, a.y, a.z, a.w, b.x, b.y, b.z, b.w};
    #pragma unroll
    for (int j = 0; j < 8; j++) {
        unsigned bits = __float_as_uint(vv[j]);
        h[j] = (unsigned short)(bits >> 16);
        float r = vv[j] - __uint_as_float(bits & 0xFFFF0000u);
        l[j] = (unsigned short)(__float_as_uint(r) >> 16);
    }
    hi = __builtin_bit_cast(frag8_t, h);
    lo = __builtin_bit_cast(frag8_t, l);
}

// async global->LDS, 16B per lane; dest = wave-uniform base + lane*16
__device__ __forceinline__ void stage16(const void* g, void* l) {
    __builtin_amdgcn_global_load_lds(
        (const __attribute__((address_space(1))) unsigned*)g,
        (__attribute__((address_space(3))) unsigned*)l, 16, 0, 0);
}

// ---------------- fused kernel: MFMA masked-MSE + region loss ----------------
// Five rounds proved VGPR-destination loads cap at ~5 in flight/wave (the
// allocator clamps to 32-68 VGPR and serializes any batch) => ~2.8 TB/s
// Little's-law ceiling. global_load_lds holds in-flight bytes in the vmem
// queue + LDS (zero VGPR), double-buffered per wave, counted vmcnt(5) --
// never 0 -- so tile t+1's 5 loads stay in flight while tile t computes.
// No barriers in the loop (wave-private slots): no forced drain.
// Consume math identical to round 8 (passed, absmax 0.0).

__global__ __launch_bounds__(THREADS) void fused_kernel(
    const float* __restrict__ user_emb,
    const float* __restrict__ item_emb,
    const int* __restrict__ train_mask,
    const float* __restrict__ true_qos,
    const float* __restrict__ us_lossweight,
    const int* __restrict__ region_index,
    float* __restrict__ loss_accum,
    float* __restrict__ rl_accum) {
    // [wave][slot][array: m,q,w,itemA,itemB][64 lanes * 16B]
    __shared__ __align__(16) char stg[4][2][5][1024];
    __shared__ float wp[THREADS / 64];
    __shared__ int   ulist[LCAP];
    __shared__ int   ucnt;
    __shared__ float part[8][D];
    __shared__ float redsum[D];

    const int lane = threadIdx.x & 63;
    const int wid  = threadIdx.x >> 6;
    const int n16  = lane & 15;     // user offset (N) / item row offset (M)
    const int g    = lane >> 4;     // k-group and C-quad group
    const int kb   = g * 8;         // this lane's k slice

    const int ub      = blockIdx.x * WU;
    const int it_base = blockIdx.y * WI + wid * (WI / 4);  // wave's 128 items

    // user B-fragment: 8 consecutive dims of one user row, loaded once
    frag8_t uh, ul;
    {
        const float* up = user_emb + (ub + n16) * D + kb;
        split8(*(const float4*)up, *(const float4*)(up + 4), uh, ul);
    }

    const unsigned soff = (unsigned)(ub + n16) * S + it_base + g * 4;
    const int*   mp  = train_mask    + soff;
    const float* qp  = true_qos      + soff;
    const float* wtp = us_lossweight + soff;
    const float* ip  = item_emb + (it_base + n16) * D + kb;

    // issue the 5 stage ops for tile t into slot (per-lane global src,
    // linear LDS dest). Exactly 5 vmem ops per ISSUE -- vmcnt counted on that.
#define ISSUE(t, slot)                                                \
    do {                                                              \
        stage16(mp + (t) * 16,           &stg[wid][slot][0][0]);      \
        stage16(qp + (t) * 16,           &stg[wid][slot][1][0]);      \
        stage16(wtp + (t) * 16,          &stg[wid][slot][2][0]);      \
        stage16(ip + (t) * 16 * D,       &stg[wid][slot][3][0]);      \
        stage16(ip + (t) * 16 * D + 4,   &stg[wid][slot][4][0]);      \
    } while (0)

    float acc = 0.0f;

    ISSUE(0, 0);                       // prologue: 5 outstanding
    #pragma unroll
    for (int t = 0; t < NT; t++) {
        const int slot = t & 1;
        if (t + 1 < NT) {
            ISSUE(t + 1, (t + 1) & 1); // 10 outstanding
            asm volatile("s_waitcnt vmcnt(5)" ::: "memory");  // tile t ready
        } else {
            asm volatile("s_waitcnt vmcnt(0)" ::: "memory");
        }
        __builtin_amdgcn_sched_barrier(0);   // rule #18: no hoisting past wait

        int4   m4 = *(const int4*)  &stg[wid][slot][0][lane * 16];
        float4 q4 = *(const float4*)&stg[wid][slot][1][lane * 16];
        float4 w4 = *(const float4*)&stg[wid][slot][2][lane * 16];
        float4 ia = *(const float4*)&stg[wid][slot][3][lane * 16];
        float4 ib = *(const float4*)&stg[wid][slot][4][lane * 16];

        frag8_t ih, il;
        split8(ia, ib, ih, il);
        fx4_t c = {0.0f, 0.0f, 0.0f, 0.0f};
        c = __builtin_amdgcn_mfma_f32_16x16x32_bf16(ih, uh, c, 0, 0, 0);
        c = __builtin_amdgcn_mfma_f32_16x16x32_bf16(il, uh, c, 0, 0, 0);
        c = __builtin_amdgcn_mfma_f32_16x16x32_bf16(ih, ul, c, 0, 0, 0);

        // c[r] = pre_qos[user=ub+n16][item = it_base + t*16 + g*4 + r]
        float p0 = c[0] * (float)m4.x; float e0 = p0 - q4.x; acc += w4.x * e0 * e0;
        float p1 = c[1] * (float)m4.y; float e1 = p1 - q4.y; acc += w4.y * e1 * e1;
        float p2 = c[2] * (float)m4.z; float e2 = p2 - q4.z; acc += w4.z * e2 * e2;
        float p3 = c[3] * (float)m4.w; float e3 = p3 - q4.w; acc += w4.w * e3 * e3;
    }
#undef ISSUE

    // wave64 reduce + one atomic per block
    #pragma unroll
    for (int off = 32; off > 0; off >>= 1) acc += __shfl_down(acc, off, 64);
    if (lane == 0) wp[wid] = acc;
    __syncthreads();
    if (threadIdx.x == 0)
        atomicAdd(loss_accum, wp[0] + wp[1] + wp[2] + wp[3]);

    // ---- region duty: blocks (r, 0) for r < NUM_REGIONS handle region r ----
    if (blockIdx.y != 0 || blockIdx.x >= NUM_REGIONS) return;
    const int r = blockIdx.x;

    __syncthreads();                 // wp reads above complete before reuse
    if (threadIdx.x == 0) ucnt = 0;
    __syncthreads();

    // parallel scan straight from global (region_index is 16 KB, L2-resident)
    for (int u = threadIdx.x; u < U; u += 256) {
        if (region_index[u] == r) {
            int p = atomicAdd(&ucnt, 1);
            if (p < LCAP) ulist[p] = u;
        }
    }
    __syncthreads();

    const int n = min(ucnt, LCAP);
    const int d = threadIdx.x & (D - 1);      // dim 0..31
    const int w8 = threadIdx.x >> 5;          // list stripe 0..7

    // pass 1: region sum over the compact list (~4 iters per stripe)
    float psum = 0.0f;
    for (int i = w8; i < n; i += 8)
        psum += user_emb[ulist[i] * D + d];
    part[w8][d] = psum;
    __syncthreads();
    if (w8 == 0) {
        float sum = 0.0f;
        #pragma unroll
        for (int i = 0; i < 8; i++) sum += part[i][d];
        redsum[d] = sum;
    }
    __syncthreads();

    // pass 2: leave-one-out deviation over the list
    float racc = 0.0f;
    if (n > 1) {
        const float inv = 1.0f / (float)(n - 1);
        const float sd = redsum[d];
        for (int i = w8; i < n; i += 8) {
            float e = user_emb[ulist[i] * D + d];
            racc += fabsf(e - (sd - e) * inv);
        }
    }

    #pragma unroll
    for (int off = 32; off > 0; off >>= 1) racc += __shfl_down(racc, off, 64);
    if (lane == 0) wp[wid] = racc;
    __syncthreads();
    if (threadIdx.x == 0)
        atomicAdd(rl_accum, wp[0] + wp[1] + wp[2] + wp[3]);
}

__global__ void finalize_kernel(const float* __restrict__ loss_acc,
                                const float* __restrict__ rl_acc,
                                float* __restrict__ out) {
    out[0] = loss_acc[0] + GA * rl_acc[0];
}

extern "C" void kernel_launch(void* const* d_in, const int* in_sizes, int n_in,
                              void* d_out, int out_size, void* d_ws, size_t ws_size,
                              hipStream_t stream) {
    const float* user_emb      = (const float*)d_in[0];
    const float* item_emb      = (const float*)d_in[1];
    const int*   train_mask    = (const int*)d_in[2];
    const float* true_qos      = (const float*)d_in[3];
    const float* us_lossweight = (const float*)d_in[4];
    const int*   region_index  = (const int*)d_in[5];
    float* out = (float*)d_out;

    float* ws       = (float*)d_ws;
    float* loss_acc = ws;          // 1
    float* rl_acc   = ws + 1;      // 1
    hipMemsetAsync(d_ws, 0, 2 * sizeof(float), stream);

    dim3 grid(U / WU, S / WI);     // (256, 16); (r<128, 0) also do region duty
    fused_kernel<<<grid, THREADS, 0, stream>>>(
        user_emb, item_emb, train_mask, true_qos, us_lossweight, region_index,
        loss_acc, rl_acc);

    finalize_kernel<<<1, 1, 0, stream>>>(loss_acc, rl_acc, out);
}